// Round 8
// baseline (33.450 us; speedup 1.0000x reference)
//
#include <hip/hip_runtime.h>
#include <math.h>

// Problem constants (match reference setup_inputs)
#define NN 2048
#define LL 16
#define EPSF 1e-10f           // f32-rounded eps, as the reference's f32 clip uses

// ws layout (8-byte aligned):
//   [0      , 16384 ): double partial[2048]
//   [16384  , 16512 ): double corr[16]
//   [16512  , 16640 ): int2   cnt[16]
//   [16640  , 20736 ): u16    colBits[16][128]   (bit r of word b = target row b*16+r)
//   [32768  , 163840): float  colS[16][2048]     (column-major scores)
//   [163840 , 294912): float  pos[16][2048]
//   [294912 , 425984): float  neg[16][2048]

static constexpr int PBLK = 2048;  // bip grid: 16 labels x 8 neg-tiles x 16 pos-chunks

// ---------------- Kernel A: coalesced transpose + target bit-pack -----------
__global__ __launch_bounds__(256) void transpose_kernel(
    const float* __restrict__ inp, const float* __restrict__ tgt,
    float* __restrict__ colS, unsigned short* __restrict__ colBits)
{
    __shared__ float         sS[16][17];   // +1 pad: 2-way max on r/w (free)
    __shared__ unsigned char sB[16][17];

    const int b = blockIdx.x;              // 128 blocks x 16 rows
    const int t = threadIdx.x;
    const int row = t >> 4, col = t & 15;

    const float v  = inp[b * 256 + t];     // coalesced: 256B contiguous per wave
    const float tv = tgt[b * 256 + t];
    sS[row][col] = v;
    sB[row][col] = (tv != 0.0f) ? (unsigned char)1 : (unsigned char)0;
    __syncthreads();

    // scores out: per col, 16 consecutive rows (64B contiguous per col)
    colS[col * 2048 + b * 16 + row] = sS[row][col];

    // bits out: one u16 per (col, block)
    if (t < 16) {
        unsigned bits = 0;
#pragma unroll
        for (int r = 0; r < 16; ++r) bits |= (unsigned)sB[r][t] << r;
        colBits[t * 128 + b] = (unsigned short)bits;
    }
}

// ---------------- Kernel B: per-label compaction + linear eps-correction ----
// Identical math/order to the verified Round-7 setup; loads now coalesced.
__global__ __launch_bounds__(256) void compact_kernel(
    const float* __restrict__ colS, const unsigned short* __restrict__ colBits,
    float* __restrict__ posA, float* __restrict__ negA,
    int2* __restrict__ cnt, double* __restrict__ corr)
{
    const int L   = blockIdx.x;       // label
    const int tid = threadIdx.x;
    const int lane = tid & 63, wid = tid >> 6;

    // this thread's 8 rows (index order): coalesced 32B from colS
    const float* colL = colS + (size_t)L * 2048;
    const float4 f0 = ((const float4*)(colL + tid * 8))[0];
    const float4 f1 = ((const float4*)(colL + tid * 8))[1];
    const float s[8] = {f0.x, f0.y, f0.z, f0.w, f1.x, f1.y, f1.z, f1.w};

    const unsigned w16  = colBits[L * 128 + (tid >> 1)];
    const unsigned bits = (w16 >> ((tid & 1) * 8)) & 0xffu;  // rows tid*8..+7

    int tg[8];
#pragma unroll
    for (int k = 0; k < 8; ++k) tg[k] = (bits >> k) & 1u;

    // local counts and neg-score sum
    int lpos = 0, lneg = 0; double lnsum = 0.0;
#pragma unroll
    for (int k = 0; k < 8; ++k) {
        if (tg[k]) ++lpos; else { ++lneg; lnsum += (double)s[k]; }
    }

    // inclusive wave scan of packed counts (pos | neg<<16) and neg-sum
    unsigned pk = (unsigned)lpos | ((unsigned)lneg << 16);
    unsigned ipk = pk; double isum = lnsum;
#pragma unroll
    for (int off = 1; off < 64; off <<= 1) {
        unsigned tu = __shfl_up(ipk, off, 64);
        double   td = __shfl_up(isum, off, 64);
        if (lane >= off) { ipk += tu; isum += td; }
    }

    __shared__ unsigned wco[4]; __shared__ double wsu[4];
    if (lane == 63) { wco[wid] = ipk; wsu[wid] = isum; }
    __syncthreads();

    unsigned basec = 0; double bases = 0.0;
    for (int w = 0; w < wid; ++w) { basec += wco[w]; bases += wsu[w]; }
    const unsigned totc = wco[0] + wco[1] + wco[2] + wco[3];
    const int npos = (int)(totc & 0xffffu);
    const int nneg = (int)(totc >> 16);

    const unsigned exc = basec + ipk - pk;   // exclusive prefix
    int    rpos  = (int)(exc & 0xffffu);
    int    rneg  = (int)(exc >> 16);
    double rnsum = bases + isum - lnsum;

    float* posL = posA + (size_t)L * 2048;
    float* negL = negA + (size_t)L * 2048;

    double cl = 0.0;   // sum over pos rows: negcnt_before*s - negsum_before
#pragma unroll
    for (int k = 0; k < 8; ++k) {
        if (tg[k]) {
            posL[rpos++] = s[k];
            cl += (double)rneg * (double)s[k] - rnsum;
        } else {
            negL[rneg++] = s[k];
            rnsum += (double)s[k];
        }
    }

    // block-reduce cl (f64)
#pragma unroll
    for (int off = 32; off > 0; off >>= 1)
        cl += __shfl_down(cl, off, 64);
    __shared__ double csh[4];
    if (lane == 0) csh[wid] = cl;
    __syncthreads();
    if (tid == 0) {
        corr[L] = csh[0] + csh[1] + csh[2] + csh[3];
        cnt[L]  = make_int2(npos, nneg);
    }

    // pad so bip tiles read blindly; pads contribute exactly 0
    const int posP = (npos + 127) & ~127;
    const int negP = (nneg + 255) & ~255;
    for (int idx = npos + tid; idx < posP; idx += 256) posL[idx] =  1e30f;
    for (int idx = nneg + tid; idx < negP; idx += 256) negL[idx] = -1e30f;
}

// ---------------- Kernel C: bipartite softplus sum --------------------------
// grid: gid = L*128 + nt*16 + pc   (nt: 256-wide neg tile, pc: 128-wide pos chunk)
__global__ __launch_bounds__(256) void bip_kernel(
    const float* __restrict__ posA, const float* __restrict__ negA,
    const int2* __restrict__ cnt, double* __restrict__ partial)
{
    const int gid = blockIdx.x;
    const int L  = gid >> 7;
    const int nt = (gid >> 4) & 7;
    const int pc = gid & 15;
    const int tid = threadIdx.x;

    const int2 c = cnt[L];                      // uniform s_load
    const int nchunkP = (c.x + 127) >> 7;       // active pos chunks
    const int ntileN  = (c.y + 255) >> 8;       // active neg tiles

    double acc = 0.0;                           // log2-domain terms
    if (nt < ntileN && pc < nchunkP) {
        const float nv = negA[(size_t)L * 2048 + nt * 256 + tid];  // coalesced
        const float4* p4 = (const float4*)(posA + (size_t)L * 2048 + pc * 128);
#pragma unroll
        for (int r = 0; r < 32; ++r) {          // 32 x float4 = 128 pos values
            const float4 pv = p4[r];            // uniform -> scalar load
            const float l0 = __log2f(1.0f + __expf(nv - pv.x));
            const float l1 = __log2f(1.0f + __expf(nv - pv.y));
            const float l2 = __log2f(1.0f + __expf(nv - pv.z));
            const float l3 = __log2f(1.0f + __expf(nv - pv.w));
            acc += (double)((l0 + l1) + (l2 + l3));
        }
    }

    const int lane = tid & 63, wid = tid >> 6;
#pragma unroll
    for (int off = 32; off > 0; off >>= 1)
        acc += __shfl_down(acc, off, 64);
    __shared__ double smem[4];
    if (lane == 0) smem[wid] = acc;
    __syncthreads();
    if (tid == 0)
        partial[gid] = smem[0] + smem[1] + smem[2] + smem[3];
}

// ---------------- Kernel D: weighted final reduce ---------------------------
__global__ __launch_bounds__(256) void final_kernel(
    const double* __restrict__ partial, const double* __restrict__ corr,
    const float* __restrict__ lw, float* __restrict__ out)
{
    const int tid = threadIdx.x;
    const double LN2 = 0.69314718055994530942;

    double acc = 0.0;
    for (int t = tid; t < PBLK; t += 256)
        acc += (double)lw[t >> 7] * (LN2 * partial[t]);
    if (tid < LL)
        acc += (double)lw[tid] * ((double)EPSF * corr[tid]);

    const int lane = tid & 63, wid = tid >> 6;
#pragma unroll
    for (int off = 32; off > 0; off >>= 1)
        acc += __shfl_down(acc, off, 64);
    __shared__ double smem[4];
    if (lane == 0) smem[wid] = acc;
    __syncthreads();
    if (tid == 0)
        out[0] = (float)((smem[0] + smem[1] + smem[2] + smem[3]) / (double)LL);
}

extern "C" void kernel_launch(void* const* d_in, const int* in_sizes, int n_in,
                              void* d_out, int out_size, void* d_ws, size_t ws_size,
                              hipStream_t stream) {
    const float* inp = (const float*)d_in[0];   // [2048, 16] f32
    const float* tgt = (const float*)d_in[1];   // [2048, 16] f32
    const float* lw  = (const float*)d_in[2];   // [16] f32
    float* out = (float*)d_out;

    char* ws = (char*)d_ws;
    double*         partial = (double*)        (ws);            // 16 KB
    double*         corr    = (double*)        (ws + 16384);    // 128 B
    int2*           cnt     = (int2*)          (ws + 16512);    // 128 B
    unsigned short* colBits = (unsigned short*)(ws + 16640);    // 4 KB
    float*          colS    = (float*)         (ws + 32768);    // 128 KB
    float*          posA    = (float*)         (ws + 163840);   // 128 KB
    float*          negA    = (float*)         (ws + 294912);   // 128 KB

    transpose_kernel<<<128, 256, 0, stream>>>(inp, tgt, colS, colBits);
    compact_kernel<<<LL, 256, 0, stream>>>(colS, colBits, posA, negA, cnt, corr);
    bip_kernel<<<PBLK, 256, 0, stream>>>(posA, negA, cnt, partial);
    final_kernel<<<1, 256, 0, stream>>>(partial, corr, lw, out);
}